// Round 6
// baseline (240.027 us; speedup 1.0000x reference)
//
#include <hip/hip_runtime.h>
#include <hip/hip_bf16.h>

// DigitCaps dynamic routing. Output fp32.
// R19: 6 dispatches with WIDE grids (R18 post-mortem: fuse1's 80-block grid
// had 1 wave/SIMD -> latency-exposed K loop; the fence-free atomic-finisher
// pattern itself verified correct). Structure:
//  - sgemm: R16 K-split MFMA (NCS=32, grid 256, 4 waves/block) but partials
//    via RETURNED atomicAdd into sAcc; last cz-block per mb (ctrS) reads
//    sAcc back (agent-scope atomic loads), divides by esum, squashes, emits
//    vB/out. squash dispatches deleted.
//  - agg2: R18-verified (agreement MFMA + bijT atomics + per-ig8 finisher
//    rebuilds 2 Bs k-blocks = exp(bij)*W) + NEW: finisher atomicAdds its
//    exp-sums into esum slot (denominator for next sgemm's normalize).
//  - deferred softmax norm: Bs unnormalized; /esum in fp32 pre-squash.
// Chain: prep | sgemm | agg2 | sgemm | agg2 | sgemm.
#define B 512
#define IC 1152
#define QD 8
#define OD 10
#define PD 16
#define KD (IC * QD)       // 9216
#define NKB (KD / 32)      // 288 K32 blocks
#define NCS 32             // K-chunks for s GEMM; grid 8*32 = 256 blocks
#define KSTEPS (NKB / NCS) // 9
#define NCB 4              // b-chunks for agreement GEMM (128 each)
#define SOP (B * OD * PD)  // 81920
#define IO (IC * OD)       // 11520
#define TPX ((B / 64) * (KD / 64))  // 8*144 = 1152 transpose tiles

typedef short bf16x8 __attribute__((ext_vector_type(8)));
typedef short bf16x4 __attribute__((ext_vector_type(4)));
typedef float f32x4 __attribute__((ext_vector_type(4)));

__device__ __forceinline__ short f2bf(float f) {
  union { float f; unsigned u; } x;
  x.f = f;
  unsigned r = x.u + 0x7FFFu + ((x.u >> 16) & 1u);  // RNE to bf16
  return (short)(r >> 16);
}

// ---------------- prep: xB + xT transpose, Bs = bf16(W), zero state ---------
__global__ __launch_bounds__(256) void prep_kernel(const float* __restrict__ x,
                                                   const float* __restrict__ W,
                                                   float* __restrict__ bijT,
                                                   float* __restrict__ sAcc,
                                                   int* __restrict__ ctrS,
                                                   int* __restrict__ ctrA,
                                                   float* __restrict__ esum,
                                                   short* __restrict__ Bs,
                                                   short* __restrict__ xB,
                                                   short* __restrict__ xT) {
  const int bid = blockIdx.x, tid = threadIdx.x;
  // distributed state zeroing (one elem per thread over the whole grid)
  {
    const int g = bid * 256 + tid;
    if (g < IO) bijT[g] = 0.f;
    const int za = g - IO;
    if (za >= 0 && za < 3 * SOP) sAcc[za] = 0.f;
    const int z = g - (IO + 3 * SOP);
    if (z >= 0) {
      if (z < 16) ctrS[z] = 0;
      else if (z < 176) ctrA[z - 16] = 0;
      else if (z < 224) esum[z - 176] = (z - 176 < 16) ? (float)IC : 0.f;
    }
  }
  if (bid < TPX) {
    // 64 b x 64 iq tile: read x fp32, emit xB (linear bf16) + xT (transposed)
    __shared__ short lds[64 * 72];  // [iq_loc][b_loc], pad 72
    const int bt = bid / (KD / 64), qt = bid % (KD / 64);
    const int b0 = bt * 64, c0 = qt * 64;
    const int row0 = tid >> 4, col4 = (tid & 15) * 4;
#pragma unroll
    for (int j = 0; j < 4; ++j) {
      const int row = row0 + j * 16;
      const float4 v = *(const float4*)(x + (size_t)(b0 + row) * KD + c0 + col4);
      bf16x4 ov;
      ov[0] = f2bf(v.x); ov[1] = f2bf(v.y); ov[2] = f2bf(v.z); ov[3] = f2bf(v.w);
      *(bf16x4*)(xB + (size_t)(b0 + row) * KD + c0 + col4) = ov;
      lds[(col4 + 0) * 72 + row] = ov[0];
      lds[(col4 + 1) * 72 + row] = ov[1];
      lds[(col4 + 2) * 72 + row] = ov[2];
      lds[(col4 + 3) * 72 + row] = ov[3];
    }
    __syncthreads();
    const int iq = tid & 63, seg = tid >> 6;  // 16 b per (iq,seg)
    const short* src = lds + iq * 72 + seg * 16;
    short* dst = xT + (size_t)(c0 + iq) * B + b0 + seg * 16;
    *(bf16x8*)dst = *(const bf16x8*)src;
    *(bf16x8*)(dst + 8) = *(const bf16x8*)(src + 8);
    return;
  }
  const int t = (bid - TPX) * 256 + tid;  // 0..46079
  const int kb = t / 160, n = t % 160;
  const int o = n >> 4, p = n & 15;
  short ov[32];
#pragma unroll
  for (int quad = 0; quad < 4; ++quad) {
    const int i = kb * 4 + quad;
    const float4* wp = (const float4*)(W + (((size_t)i * OD + o) * PD + p) * QD);
    const float4 w0 = wp[0], w1 = wp[1];
    ov[quad * 8 + 0] = f2bf(w0.x); ov[quad * 8 + 1] = f2bf(w0.y);
    ov[quad * 8 + 2] = f2bf(w0.z); ov[quad * 8 + 3] = f2bf(w0.w);
    ov[quad * 8 + 4] = f2bf(w1.x); ov[quad * 8 + 5] = f2bf(w1.y);
    ov[quad * 8 + 6] = f2bf(w1.z); ov[quad * 8 + 7] = f2bf(w1.w);
  }
  int4* dst = (int4*)(Bs + (size_t)t * 32);
  const int4* src = (const int4*)ov;
#pragma unroll
  for (int j = 0; j < 4; ++j) dst[j] = src[j];
}

// ---------------- sgemm: K-split MFMA + atomic sAcc + finisher squash -------
// grid 8*NCS blocks; cz = bid%NCS, mb = bid/NCS. Finisher = last cz of mb.
__global__ __launch_bounds__(256) void sgemm_kernel(const short* __restrict__ xB,
                                                    const short* __restrict__ Bs,
                                                    const float* __restrict__ esum_in,
                                                    float* __restrict__ sAcc,
                                                    int* __restrict__ ctrS,
                                                    short* __restrict__ vB,
                                                    float* __restrict__ out,
                                                    int write_out) {
  const int tid = threadIdx.x;
  const int wave = tid >> 6, lane = tid & 63;
  const int ln = lane & 15, quad = lane >> 4;
  const int cz = blockIdx.x % NCS, mb = blockIdx.x / NCS;
  const int m0 = mb * 64 + wave * 16;
  f32x4 acc[10] = {};
  const short* arow = xB + (size_t)(m0 + ln) * KD + quad * 8;
#pragma unroll
  for (int step = 0; step < KSTEPS; ++step) {
    const int kb = cz * KSTEPS + step;
    const bf16x8 af = *(const bf16x8*)(arow + kb * 32);
    const short* bp = Bs + (size_t)kb * 5120 + ln * 32 + quad * 8;
#pragma unroll
    for (int nt = 0; nt < 10; ++nt) {
      const bf16x8 bf = *(const bf16x8*)(bp + nt * 512);
      acc[nt] = __builtin_amdgcn_mfma_f32_16x16x32_bf16(af, bf, acc[nt], 0, 0, 0);
    }
  }
  // returned atomic adds -> completion at coherence point before ctr bump
  float snk = 0.f;
#pragma unroll
  for (int nt = 0; nt < 10; ++nt)
#pragma unroll
    for (int r = 0; r < 4; ++r)
      snk += atomicAdd(&sAcc[(size_t)(m0 + quad * 4 + r) * 160 + nt * 16 + ln],
                       acc[nt][r]);
  asm volatile("" :: "v"(snk));
  __syncthreads();
  __shared__ int flag;
  __shared__ float einv[OD];
  if (tid == 0)
    flag = (__hip_atomic_fetch_add(&ctrS[mb], 1, __ATOMIC_RELAXED,
                                   __HIP_MEMORY_SCOPE_AGENT) == NCS - 1) ? 1 : 0;
  __syncthreads();
  if (!flag) return;
  if (tid == 0)
    __hip_atomic_store(&ctrS[mb], 0, __ATOMIC_RELAXED, __HIP_MEMORY_SCOPE_AGENT);
  if (tid < OD) einv[tid] = 1.f / esum_in[tid];  // prev-dispatch data: plain ok
  __syncthreads();
  // finisher: normalize + squash 64 rows (atomic loads bypass stale L2)
#pragma unroll
  for (int vb = 0; vb < 40; ++vb) {
    const int t = mb * 10240 + vb * 256 + tid;  // t = b*160 + n
    const float sv = __hip_atomic_load(&sAcc[t], __ATOMIC_RELAXED,
                                       __HIP_MEMORY_SCOPE_AGENT) *
                     einv[(t % 160) >> 4];
    float sq = sv * sv;
#pragma unroll
    for (int m = 1; m < 16; m <<= 1) sq += __shfl_xor(sq, m, 16);
    const float norm = sqrtf(sq + 1e-8f);
    const float val = sv * (sq / ((1.f + sq) * norm));
    if (write_out) {
      out[t] = val;
    } else {
      const int b = t / 160, n = t - b * 160;
      vB[((size_t)(b >> 5) * 160 + n) * 32 + (b & 31)] = f2bf(val);
    }
  }
}

// ---------------- agg2: bijT += agreement; finisher: Bs slice + esum --------
// grid (144 ig8, 4 kq). G[m=(i8q),(n=o*16+p)] = sum_b xT[iq][b]*v[b][op].
__global__ __launch_bounds__(256) void agg2_kernel(const short* __restrict__ xT,
                                                   const float* __restrict__ W,
                                                   const short* __restrict__ vB,
                                                   float* __restrict__ bijT,
                                                   short* __restrict__ Bs,
                                                   int* __restrict__ ctrA,
                                                   float* __restrict__ esumOut) {
  const int tid = threadIdx.x;
  const int ig8 = blockIdx.x, kq = blockIdx.y;
  const int mt = tid >> 6, lane = tid & 63;
  const int ln = lane & 15, quad = lane >> 4;
  f32x4 acc[10] = {};
  const short* arow = xT + (size_t)(ig8 * 64 + mt * 16 + ln) * B + kq * 128 + quad * 8;
#pragma unroll
  for (int kb = 0; kb < 4; ++kb) {
    const bf16x8 af = *(const bf16x8*)(arow + kb * 32);
    const short* bp = vB + ((size_t)(kq * 4 + kb) * 160 + ln) * 32 + quad * 8;
#pragma unroll
    for (int nt = 0; nt < 10; ++nt) {
      const bf16x8 bf = *(const bf16x8*)(bp + nt * 512);
      acc[nt] = __builtin_amdgcn_mfma_f32_16x16x32_bf16(af, bf, acc[nt], 0, 0, 0);
    }
  }
  // epilogue: contract G with W -> agreement; RETURNED atomics (ordering!)
  const int i = ig8 * 8 + mt * 2 + (quad >> 1);
  const int qb = (quad & 1) * 4;
  float rsum = 0.f;
#pragma unroll
  for (int nt = 0; nt < 10; ++nt) {
    const float4 wv = *(const float4*)(W + (((size_t)i * OD + nt) * PD + ln) * QD + qb);
    float pa = acc[nt][0] * wv.x + acc[nt][1] * wv.y + acc[nt][2] * wv.z + acc[nt][3] * wv.w;
    pa += __shfl_xor(pa, 1); pa += __shfl_xor(pa, 2); pa += __shfl_xor(pa, 4);
    pa += __shfl_xor(pa, 8); pa += __shfl_xor(pa, 16);
    if ((lane & 31) == 0)
      rsum += atomicAdd(&bijT[(size_t)nt * IC + i], pa * (1.0f / (float)B));
  }
  asm volatile("" :: "v"(rsum));
  __syncthreads();
  __shared__ int flag;
  __shared__ float eL[8][OD];
  if (tid == 0)
    flag = (__hip_atomic_fetch_add(&ctrA[ig8], 1, __ATOMIC_RELAXED,
                                   __HIP_MEMORY_SCOPE_AGENT) == NCB - 1) ? 1 : 0;
  __syncthreads();
  if (!flag) return;
  // finisher: rebuild Bs k-blocks [ig8*2, ig8*2+1] = exp(bij)*W (unnormalized)
  if (tid < 8 * OD) {
    const int il = tid / OD, o = tid - il * OD;
    const float bv = __hip_atomic_load(&bijT[(size_t)o * IC + ig8 * 8 + il],
                                       __ATOMIC_RELAXED, __HIP_MEMORY_SCOPE_AGENT);
    eL[il][o] = __expf(bv);
  }
  if (tid == 0)
    __hip_atomic_store(&ctrA[ig8], 0, __ATOMIC_RELAXED, __HIP_MEMORY_SCOPE_AGENT);
  __syncthreads();
  if (tid < OD) {  // softmax denominator contribution for this ig8's 8 i's
    float s = 0.f;
#pragma unroll
    for (int il = 0; il < 8; ++il) s += eL[il][tid];
    atomicAdd(&esumOut[tid], s);
  }
  for (int vb = tid; vb < 320; vb += 256) {
    const int kbl = vb / 160, n = vb - kbl * 160;
    const int kb = ig8 * 2 + kbl;
    const int o = n >> 4, pp = n & 15;
    short ov[32];
#pragma unroll
    for (int q4 = 0; q4 < 4; ++q4) {
      const int ii = kb * 4 + q4;
      const float ci = eL[ii - ig8 * 8][o];
      const float4* wp = (const float4*)(W + (((size_t)ii * OD + o) * PD + pp) * QD);
      const float4 w0 = wp[0], w1 = wp[1];
      ov[q4 * 8 + 0] = f2bf(ci * w0.x); ov[q4 * 8 + 1] = f2bf(ci * w0.y);
      ov[q4 * 8 + 2] = f2bf(ci * w0.z); ov[q4 * 8 + 3] = f2bf(ci * w0.w);
      ov[q4 * 8 + 4] = f2bf(ci * w1.x); ov[q4 * 8 + 5] = f2bf(ci * w1.y);
      ov[q4 * 8 + 6] = f2bf(ci * w1.z); ov[q4 * 8 + 7] = f2bf(ci * w1.w);
    }
    int4* dst = (int4*)(Bs + (size_t)(kb * 160 + n) * 32);
    const int4* src = (const int4*)ov;
#pragma unroll
    for (int j = 0; j < 4; ++j) dst[j] = src[j];
  }
}

// ---------------- launch: 6 dispatches --------------------------------------

extern "C" void kernel_launch(void* const* d_in, const int* in_sizes, int n_in,
                              void* d_out, int out_size, void* d_ws, size_t ws_size,
                              hipStream_t stream) {
  const float* x = (const float*)d_in[0];  // [512,1152,8] fp32
  const float* W = (const float*)d_in[1];  // [1152,10,16,8] fp32
  float* out = (float*)d_out;              // [512,10,16] fp32

  // workspace ~24 MB; every buffer written before read per call
  float* bijT = (float*)d_ws;                          // 11520 f
  float* sAcc = bijT + IO;                             // 3*81920 f
  int* ctrS = (int*)(sAcc + (size_t)3 * SOP);          // 16 i
  int* ctrA = ctrS + 16;                               // 160 i
  float* esum = (float*)(ctrA + 160);                  // 3*16 f (pad 64)
  short* vB = (short*)(esum + 64);                     // 16*160*32 shorts
  short* Bs = vB + (size_t)16 * 160 * 32;              // 288*160*32 shorts
  short* xB = Bs + (size_t)NKB * 160 * 32;             // 512*9216 shorts
  short* xT = xB + (size_t)B * KD;                     // 9216*512 shorts

  const dim3 agrid(144, NCB);

  prep_kernel<<<TPX + 180, 256, 0, stream>>>(x, W, bijT, sAcc, ctrS, ctrA, esum,
                                             Bs, xB, xT);
  // iter 1 (esum slot0 pre-set to IC by prep)
  sgemm_kernel<<<8 * NCS, 256, 0, stream>>>(xB, Bs, esum, sAcc, ctrS, vB, out, 0);
  agg2_kernel<<<agrid, 256, 0, stream>>>(xT, W, vB, bijT, Bs, ctrA, esum + 16);
  // iter 2
  sgemm_kernel<<<8 * NCS, 256, 0, stream>>>(xB, Bs, esum + 16, sAcc + SOP, ctrS,
                                            vB, out, 0);
  agg2_kernel<<<agrid, 256, 0, stream>>>(xT, W, vB, bijT, Bs, ctrA, esum + 32);
  // iter 3
  sgemm_kernel<<<8 * NCS, 256, 0, stream>>>(xB, Bs, esum + 32, sAcc + (size_t)2 * SOP,
                                            ctrS, vB, out, 1);
}

// Round 7
// 173.344 us; speedup vs baseline: 1.3847x; 1.3847x over previous
//
#include <hip/hip_runtime.h>
#include <hip/hip_bf16.h>

// DigitCaps dynamic routing. Output fp32.
// R20: R19 with the sgemm reduction de-atomicized. R19 post-mortem: 2.6M
// returned device-scope fp32 atomicAdds into sAcc = 46us/dispatch (memory-
// side, uncombined, 64B-granule). Replace with:
//  - sgemm blocks = 16-row M-tile x full N; 4 waves split K (NCS=12 chunks x
//    4 waves = 48 x 6 K32-steps); LDS-reduce wave partials; ONE coalesced
//    agent-scope write-through store of the 2560-float partial per block
//    (983K stores total, no read-return, no contention).
//  - finisher protocol unchanged (R18/R19-verified): vmcnt drain + barrier ->
//    relaxed agent fetch_add ctrS -> last block agent-loads 12 partials,
//    normalizes by esum, squashes, emits vB/out.
//  - agg2 (agreement MFMA + bijT atomics + per-ig8 Bs-slice + esum finisher)
//    and deferred softmax norm carried over unchanged.
// Chain: prep | sgemm | agg2 | sgemm | agg2 | sgemm  (6 dispatches).
#define B 512
#define IC 1152
#define QD 8
#define OD 10
#define PD 16
#define KD (IC * QD)       // 9216
#define NKB (KD / 32)      // 288 K32 blocks
#define NCS 12             // K-chunks for s GEMM; grid 32*12 = 384 blocks
#define KSTEPS 6           // 288 / (NCS*4 waves)
#define MB 32              // M-tiles (16 rows each)
#define NCB 4              // b-chunks for agreement GEMM (128 each)
#define SOP (B * OD * PD)  // 81920
#define IO (IC * OD)       // 11520
#define TPX ((B / 64) * (KD / 64))  // 8*144 = 1152 transpose tiles

typedef short bf16x8 __attribute__((ext_vector_type(8)));
typedef short bf16x4 __attribute__((ext_vector_type(4)));
typedef float f32x4 __attribute__((ext_vector_type(4)));

__device__ __forceinline__ short f2bf(float f) {
  union { float f; unsigned u; } x;
  x.f = f;
  unsigned r = x.u + 0x7FFFu + ((x.u >> 16) & 1u);  // RNE to bf16
  return (short)(r >> 16);
}

// ---------------- prep: xB + xT transpose, Bs = bf16(W), zero state ---------
__global__ __launch_bounds__(256) void prep_kernel(const float* __restrict__ x,
                                                   const float* __restrict__ W,
                                                   float* __restrict__ bijT,
                                                   int* __restrict__ ctrS,
                                                   int* __restrict__ ctrA,
                                                   float* __restrict__ esum,
                                                   short* __restrict__ Bs,
                                                   short* __restrict__ xB,
                                                   short* __restrict__ xT) {
  const int bid = blockIdx.x, tid = threadIdx.x;
  // distributed state zeroing
  {
    const int g = bid * 256 + tid;
    if (g < IO) bijT[g] = 0.f;
    const int z = g - IO;
    if (z >= 0) {
      if (z < 32) ctrS[z] = 0;
      else if (z < 192) ctrA[z - 32] = 0;
      else if (z < 240) esum[z - 192] = (z - 192 < 16) ? (float)IC : 0.f;
    }
  }
  if (bid < TPX) {
    // 64 b x 64 iq tile: read x fp32, emit xB (linear bf16) + xT (transposed)
    __shared__ short lds[64 * 72];  // [iq_loc][b_loc], pad 72
    const int bt = bid / (KD / 64), qt = bid % (KD / 64);
    const int b0 = bt * 64, c0 = qt * 64;
    const int row0 = tid >> 4, col4 = (tid & 15) * 4;
#pragma unroll
    for (int j = 0; j < 4; ++j) {
      const int row = row0 + j * 16;
      const float4 v = *(const float4*)(x + (size_t)(b0 + row) * KD + c0 + col4);
      bf16x4 ov;
      ov[0] = f2bf(v.x); ov[1] = f2bf(v.y); ov[2] = f2bf(v.z); ov[3] = f2bf(v.w);
      *(bf16x4*)(xB + (size_t)(b0 + row) * KD + c0 + col4) = ov;
      lds[(col4 + 0) * 72 + row] = ov[0];
      lds[(col4 + 1) * 72 + row] = ov[1];
      lds[(col4 + 2) * 72 + row] = ov[2];
      lds[(col4 + 3) * 72 + row] = ov[3];
    }
    __syncthreads();
    const int iq = tid & 63, seg = tid >> 6;  // 16 b per (iq,seg)
    const short* src = lds + iq * 72 + seg * 16;
    short* dst = xT + (size_t)(c0 + iq) * B + b0 + seg * 16;
    *(bf16x8*)dst = *(const bf16x8*)src;
    *(bf16x8*)(dst + 8) = *(const bf16x8*)(src + 8);
    return;
  }
  const int t = (bid - TPX) * 256 + tid;  // 0..46079
  const int kb = t / 160, n = t % 160;
  const int o = n >> 4, p = n & 15;
  short ov[32];
#pragma unroll
  for (int quad = 0; quad < 4; ++quad) {
    const int i = kb * 4 + quad;
    const float4* wp = (const float4*)(W + (((size_t)i * OD + o) * PD + p) * QD);
    const float4 w0 = wp[0], w1 = wp[1];
    ov[quad * 8 + 0] = f2bf(w0.x); ov[quad * 8 + 1] = f2bf(w0.y);
    ov[quad * 8 + 2] = f2bf(w0.z); ov[quad * 8 + 3] = f2bf(w0.w);
    ov[quad * 8 + 4] = f2bf(w1.x); ov[quad * 8 + 5] = f2bf(w1.y);
    ov[quad * 8 + 6] = f2bf(w1.z); ov[quad * 8 + 7] = f2bf(w1.w);
  }
  int4* dst = (int4*)(Bs + (size_t)t * 32);
  const int4* src = (const int4*)ov;
#pragma unroll
  for (int j = 0; j < 4; ++j) dst[j] = src[j];
}

// ---------------- sgemm: 16-row tile, 4-wave K-split, coalesced WT stores ---
// grid MB*NCS; mb = bid/NCS, cz = bid%NCS. Finisher = last cz of mb.
__global__ __launch_bounds__(256) void sgemm_kernel(const short* __restrict__ xB,
                                                    const short* __restrict__ Bs,
                                                    const float* __restrict__ esum_in,
                                                    float* __restrict__ s_part,
                                                    int* __restrict__ ctrS,
                                                    short* __restrict__ vB,
                                                    float* __restrict__ out,
                                                    int write_out) {
  __shared__ float sbuf[4][16][168];  // 43KB, +8 pad
  __shared__ int flag;
  __shared__ float einv[OD];
  const int tid = threadIdx.x;
  const int wave = tid >> 6, lane = tid & 63;
  const int ln = lane & 15, quad = lane >> 4;
  const int cz = blockIdx.x % NCS, mb = blockIdx.x / NCS;
  const int m0 = mb * 16;
  const int czw = cz * 4 + wave;  // 0..47 K-chunks of 6 K32-steps
  f32x4 acc[10] = {};
  const short* arow = xB + (size_t)(m0 + ln) * KD + quad * 8;
#pragma unroll
  for (int step = 0; step < KSTEPS; ++step) {
    const int kb = czw * KSTEPS + step;
    const bf16x8 af = *(const bf16x8*)(arow + (size_t)kb * 32);
    const short* bp = Bs + (size_t)kb * 5120 + ln * 32 + quad * 8;
#pragma unroll
    for (int nt = 0; nt < 10; ++nt) {
      const bf16x8 bf = *(const bf16x8*)(bp + nt * 512);
      acc[nt] = __builtin_amdgcn_mfma_f32_16x16x32_bf16(af, bf, acc[nt], 0, 0, 0);
    }
  }
  // wave partials -> LDS (C layout: row=quad*4+r, col=nt*16+ln)
#pragma unroll
  for (int nt = 0; nt < 10; ++nt)
#pragma unroll
    for (int r = 0; r < 4; ++r)
      sbuf[wave][quad * 4 + r][nt * 16 + ln] = acc[nt][r];
  __syncthreads();
  // block partial = sum of 4 waves; coalesced agent write-through stores
#pragma unroll
  for (int j = 0; j < 10; ++j) {
    const int e = tid + j * 256;  // 0..2559
    const int row = e / 160, col = e % 160;
    const float v = sbuf[0][row][col] + sbuf[1][row][col] +
                    sbuf[2][row][col] + sbuf[3][row][col];
    __hip_atomic_store(&s_part[((size_t)cz * B + m0 + row) * 160 + col], v,
                       __ATOMIC_RELAXED, __HIP_MEMORY_SCOPE_AGENT);
  }
  asm volatile("s_waitcnt vmcnt(0)" ::: "memory");  // stores at coherence point
  __syncthreads();
  if (tid == 0)
    flag = (__hip_atomic_fetch_add(&ctrS[mb], 1, __ATOMIC_RELAXED,
                                   __HIP_MEMORY_SCOPE_AGENT) == NCS - 1) ? 1 : 0;
  __syncthreads();
  if (!flag) return;
  if (tid == 0)
    __hip_atomic_store(&ctrS[mb], 0, __ATOMIC_RELAXED, __HIP_MEMORY_SCOPE_AGENT);
  if (tid < OD) einv[tid] = 1.f / esum_in[tid];  // prev-dispatch data
  __syncthreads();
  // finisher: sum 12 partials (agent loads), normalize, squash, emit
  const int row = tid >> 4, p = tid & 15;
#pragma unroll
  for (int o = 0; o < OD; ++o) {
    float sv = 0.f;
#pragma unroll
    for (int c2 = 0; c2 < NCS; ++c2)
      sv += __hip_atomic_load(&s_part[((size_t)c2 * B + m0 + row) * 160 + o * 16 + p],
                              __ATOMIC_RELAXED, __HIP_MEMORY_SCOPE_AGENT);
    sv *= einv[o];
    float sq = sv * sv;
#pragma unroll
    for (int m = 1; m < 16; m <<= 1) sq += __shfl_xor(sq, m, 16);
    const float norm = sqrtf(sq + 1e-8f);
    const float val = sv * (sq / ((1.f + sq) * norm));
    const int b = m0 + row, n = o * 16 + p;
    if (write_out) {
      out[(size_t)b * 160 + n] = val;
    } else {
      vB[((size_t)(b >> 5) * 160 + n) * 32 + (b & 31)] = f2bf(val);
    }
  }
}

// ---------------- agg2: bijT += agreement; finisher: Bs slice + esum --------
// grid (144 ig8, 4 kq). G[m=(i8q),(n=o*16+p)] = sum_b xT[iq][b]*v[b][op].
__global__ __launch_bounds__(256) void agg2_kernel(const short* __restrict__ xT,
                                                   const float* __restrict__ W,
                                                   const short* __restrict__ vB,
                                                   float* __restrict__ bijT,
                                                   short* __restrict__ Bs,
                                                   int* __restrict__ ctrA,
                                                   float* __restrict__ esumOut) {
  const int tid = threadIdx.x;
  const int ig8 = blockIdx.x, kq = blockIdx.y;
  const int mt = tid >> 6, lane = tid & 63;
  const int ln = lane & 15, quad = lane >> 4;
  f32x4 acc[10] = {};
  const short* arow = xT + (size_t)(ig8 * 64 + mt * 16 + ln) * B + kq * 128 + quad * 8;
#pragma unroll
  for (int kb = 0; kb < 4; ++kb) {
    const bf16x8 af = *(const bf16x8*)(arow + kb * 32);
    const short* bp = vB + ((size_t)(kq * 4 + kb) * 160 + ln) * 32 + quad * 8;
#pragma unroll
    for (int nt = 0; nt < 10; ++nt) {
      const bf16x8 bf = *(const bf16x8*)(bp + nt * 512);
      acc[nt] = __builtin_amdgcn_mfma_f32_16x16x32_bf16(af, bf, acc[nt], 0, 0, 0);
    }
  }
  // epilogue: contract G with W -> agreement; RETURNED atomics (ordering!)
  const int i = ig8 * 8 + mt * 2 + (quad >> 1);
  const int qb = (quad & 1) * 4;
  float rsum = 0.f;
#pragma unroll
  for (int nt = 0; nt < 10; ++nt) {
    const float4 wv = *(const float4*)(W + (((size_t)i * OD + nt) * PD + ln) * QD + qb);
    float pa = acc[nt][0] * wv.x + acc[nt][1] * wv.y + acc[nt][2] * wv.z + acc[nt][3] * wv.w;
    pa += __shfl_xor(pa, 1); pa += __shfl_xor(pa, 2); pa += __shfl_xor(pa, 4);
    pa += __shfl_xor(pa, 8); pa += __shfl_xor(pa, 16);
    if ((lane & 31) == 0)
      rsum += atomicAdd(&bijT[(size_t)nt * IC + i], pa * (1.0f / (float)B));
  }
  asm volatile("" :: "v"(rsum));
  __syncthreads();
  __shared__ int flag;
  __shared__ float eL[8][OD];
  if (tid == 0)
    flag = (__hip_atomic_fetch_add(&ctrA[ig8], 1, __ATOMIC_RELAXED,
                                   __HIP_MEMORY_SCOPE_AGENT) == NCB - 1) ? 1 : 0;
  __syncthreads();
  if (!flag) return;
  // finisher: rebuild Bs k-blocks [ig8*2, ig8*2+1] = exp(bij)*W (unnormalized)
  if (tid < 8 * OD) {
    const int il = tid / OD, o = tid - il * OD;
    const float bv = __hip_atomic_load(&bijT[(size_t)o * IC + ig8 * 8 + il],
                                       __ATOMIC_RELAXED, __HIP_MEMORY_SCOPE_AGENT);
    eL[il][o] = __expf(bv);
  }
  if (tid == 0)
    __hip_atomic_store(&ctrA[ig8], 0, __ATOMIC_RELAXED, __HIP_MEMORY_SCOPE_AGENT);
  __syncthreads();
  if (tid < OD) {  // softmax denominator contribution for this ig8's 8 i's
    float s = 0.f;
#pragma unroll
    for (int il = 0; il < 8; ++il) s += eL[il][tid];
    atomicAdd(&esumOut[tid], s);
  }
  for (int vb = tid; vb < 320; vb += 256) {
    const int kbl = vb / 160, n = vb - kbl * 160;
    const int kb = ig8 * 2 + kbl;
    const int o = n >> 4, pp = n & 15;
    short ov[32];
#pragma unroll
    for (int q4 = 0; q4 < 4; ++q4) {
      const int ii = kb * 4 + q4;
      const float ci = eL[ii - ig8 * 8][o];
      const float4* wp = (const float4*)(W + (((size_t)ii * OD + o) * PD + pp) * QD);
      const float4 w0 = wp[0], w1 = wp[1];
      ov[q4 * 8 + 0] = f2bf(ci * w0.x); ov[q4 * 8 + 1] = f2bf(ci * w0.y);
      ov[q4 * 8 + 2] = f2bf(ci * w0.z); ov[q4 * 8 + 3] = f2bf(ci * w0.w);
      ov[q4 * 8 + 4] = f2bf(ci * w1.x); ov[q4 * 8 + 5] = f2bf(ci * w1.y);
      ov[q4 * 8 + 6] = f2bf(ci * w1.z); ov[q4 * 8 + 7] = f2bf(ci * w1.w);
    }
    int4* dst = (int4*)(Bs + (size_t)(kb * 160 + n) * 32);
    const int4* src = (const int4*)ov;
#pragma unroll
    for (int j = 0; j < 4; ++j) dst[j] = src[j];
  }
}

// ---------------- launch: 6 dispatches --------------------------------------

extern "C" void kernel_launch(void* const* d_in, const int* in_sizes, int n_in,
                              void* d_out, int out_size, void* d_ws, size_t ws_size,
                              hipStream_t stream) {
  const float* x = (const float*)d_in[0];  // [512,1152,8] fp32
  const float* W = (const float*)d_in[1];  // [1152,10,16,8] fp32
  float* out = (float*)d_out;              // [512,10,16] fp32

  // workspace ~25 MB; every buffer written before read per call
  float* bijT = (float*)d_ws;                          // 11520 f
  float* s_part = bijT + IO;                           // 12*512*160 f
  int* ctrS = (int*)(s_part + (size_t)NCS * B * 160);  // 32 i
  int* ctrA = ctrS + 32;                               // 160 i
  float* esum = (float*)(ctrA + 160);                  // 48 f (pad 64)
  short* vB = (short*)(esum + 64);                     // 16*160*32 shorts
  short* Bs = vB + (size_t)16 * 160 * 32;              // 288*160*32 shorts
  short* xB = Bs + (size_t)NKB * 160 * 32;             // 512*9216 shorts
  short* xT = xB + (size_t)B * KD;                     // 9216*512 shorts

  const dim3 agrid(144, NCB);

  prep_kernel<<<TPX + 180, 256, 0, stream>>>(x, W, bijT, ctrS, ctrA, esum,
                                             Bs, xB, xT);
  // iter 1 (esum slot0 pre-set to IC by prep)
  sgemm_kernel<<<MB * NCS, 256, 0, stream>>>(xB, Bs, esum, s_part, ctrS, vB, out, 0);
  agg2_kernel<<<agrid, 256, 0, stream>>>(xT, W, vB, bijT, Bs, ctrA, esum + 16);
  // iter 2
  sgemm_kernel<<<MB * NCS, 256, 0, stream>>>(xB, Bs, esum + 16, s_part, ctrS, vB, out, 0);
  agg2_kernel<<<agrid, 256, 0, stream>>>(xT, W, vB, bijT, Bs, ctrA, esum + 32);
  // iter 3
  sgemm_kernel<<<MB * NCS, 256, 0, stream>>>(xB, Bs, esum + 32, s_part, ctrS, vB, out, 1);
}